// Round 1
// baseline (482.816 us; speedup 1.0000x reference)
//
#include <hip/hip_runtime.h>
#include <hip/hip_bf16.h>

#define FDIM 60
#define MROW 600
#define CDIM 8
#define ODIM 18
#define CH   128
#define NCHUNK 5
#define BLK  512

typedef short bf16x8 __attribute__((ext_vector_type(8)));
typedef float f32x4  __attribute__((ext_vector_type(4)));

// RNE pack two fp32 -> bf16x2 via v_cvt_pk_bf16_f32 (lo = low half, hi = high half)
__device__ __forceinline__ unsigned int pk2(float lo, float hi) {
    __hip_bfloat162 h2 = __float22bfloat162_rn(make_float2(lo, hi));
    unsigned int u;
    __builtin_memcpy(&u, &h2, sizeof(u));
    return u;
}
__device__ __forceinline__ short f2bf(float f) {
    __hip_bfloat16 h = __float2bfloat16(f);
    short s;
    __builtin_memcpy(&s, &h, sizeof(s));
    return s;
}

__global__ void __launch_bounds__(BLK, 6) netfv_kernel(
    const float* __restrict__ x,      // [B*M, F] fp32
    const float* __restrict__ W,      // [F, C]
    const float* __restrict__ covar,  // [F, C]
    const float* __restrict__ bias,   // [C]
    const float* __restrict__ cw2,    // [1, F, C]
    const float* __restrict__ H,      // [2*C*F, OUT]
    float* __restrict__ out)          // [B, OUT]
{
    // LDS budget: 17408*2 + 4352 + 2304 + 4096 + 3840 + 512 + 136 = 50,056 B
    // -> 3 blocks/CU (was 68.5 KB -> 2 blocks/CU)
    __shared__ __align__(16) short xsT1[64 * 136];   // x   [f][m] k-major, swizzled
    __shared__ __align__(16) short xsT2[64 * 136];   // x^2 [f][m] k-major, swizzled
    __shared__ __align__(16) short actT[16 * 136];   // act [c][m] k-major (c>=8 zero)
    __shared__ __align__(16) short WtB [16 * 72];    // W^T bf16 (c>=8 / f>=60 zero)
    __shared__ __align__(16) float fvbuf[1024];      // raw fv1|fv2 [f*8+c]
    __shared__ __align__(16) float fvl[960];
    __shared__ float redA[64], redB[64];
    __shared__ float asuml[8], n1rs[8], n1c_s[8], n2c_s[8], scal[2];

    const int tid  = threadIdx.x;
    const int b    = blockIdx.x;
    const int lane = tid & 63;
    const int wv   = tid >> 6;
    const int mg   = tid >> 3;      // row-pair 0..63
    const int fs   = tid & 7;       // f-slice (8 floats)
    const int ln15 = lane & 15;
    const int quad = lane >> 4;
    const int fvsel = wv & 1;       // 0: fv1 (x), 1: fv2 (x^2)
    const int tile  = wv >> 1;      // f-tile 0..3

    const size_t rowbase = (size_t)b * (MROW * FDIM);
    const float* prow = x + rowbase + (size_t)(2 * mg) * FDIM + 8 * fs;

    // preload chunk 0 staging data early (overlap with init)
    float4 A0, A1, B0, B1;
    B0 = B1 = make_float4(0.f, 0.f, 0.f, 0.f);
    A0 = *(const float4*)prow;
    A1 = *(const float4*)(prow + FDIM);
    if (fs < 7) { B0 = *(const float4*)(prow + 4); B1 = *(const float4*)(prow + FDIM + 4); }

    // --- one-time init: WtB (bf16 W^T, zero-padded), actT rows 8..15 zero ---
    {
        int c = tid >> 5, j = tid & 31;
        float v0 = (2 * j     < FDIM) ? W[(2 * j) * CDIM + (c & 7)]     : 0.f;
        float v1 = (2 * j + 1 < FDIM) ? W[(2 * j + 1) * CDIM + (c & 7)] : 0.f;
        if (c >= CDIM) { v0 = 0.f; v1 = 0.f; }
        ((unsigned int*)WtB)[c * 36 + j] = pk2(v0, v1);
    }
    {
        unsigned int* az = (unsigned int*)(actT + 8 * 136);
        for (int i = tid; i < 544; i += BLK) az[i] = 0u;
    }
    __syncthreads();

    // hoisted W A-fragments (constant across chunks) + bias fragment
    const bf16x8 aw0 = *(const bf16x8*)(WtB + ln15 * 72 + quad * 8);
    const bf16x8 aw1 = *(const bf16x8*)(WtB + ln15 * 72 + 32 + quad * 8);
    const float4 lb  = *(const float4*)(bias + (quad & 1) * 4);

    f32x4 acc = {0.f, 0.f, 0.f, 0.f};
    float asum_acc[4] = {0.f, 0.f, 0.f, 0.f};
    const int mloc = wv * 16 + ln15;      // local m handled in logits phase

    for (int ck = 0; ck < NCHUNK; ++ck) {
        const bool valid = (ck * CH + 2 * mg) < MROW;

        // --- prefetch next chunk's staging data into registers (HBM) ---
        float4 nA0, nA1, nB0, nB1;
        nA0 = nA1 = nB0 = nB1 = make_float4(0.f, 0.f, 0.f, 0.f);
        if (ck + 1 < NCHUNK && ((ck + 1) * CH + 2 * mg) < MROW) {
            const float* pn = prow + (size_t)(ck + 1) * (CH * FDIM);
            nA0 = *(const float4*)pn;
            nA1 = *(const float4*)(pn + FDIM);
            if (fs < 7) { nB0 = *(const float4*)(pn + 4); nB1 = *(const float4*)(pn + FDIM + 4); }
        }

        // --- issue logits-row loads for THIS chunk (L2-hot: same lines the
        //     staging prefetch pulled one chunk ago). Per-lane row = mloc. ---
        const int grow = ck * CH + mloc;
        const bool vm = grow < MROW;
        const float* xr = x + rowbase + (size_t)(vm ? grow : (MROW - 1)) * FDIM;
        float4 c0 = *(const float4*)(xr + quad * 8);
        float4 c1 = *(const float4*)(xr + quad * 8 + 4);
        float4 c2 = *(const float4*)(xr + 32 + quad * 8);
        float4 c3 = (quad < 3) ? *(const float4*)(xr + 36 + quad * 8)
                               : make_float4(0.f, 0.f, 0.f, 0.f);  // f60..63: W is zero there

        // --- stage current chunk to LDS: f-major x and x^2 (swizzled) ---
        if (valid) {
            float xv0[8] = {A0.x, A0.y, A0.z, A0.w, B0.x, B0.y, B0.z, B0.w};
            float xv1[8] = {A1.x, A1.y, A1.z, A1.w, B1.x, B1.y, B1.z, B1.w};
            const int wbase = (((mg >> 2) ^ fs) << 2) + (mg & 3);
            #pragma unroll
            for (int i = 0; i < 8; ++i) {
                int woff = (8 * fs + i) * 68 + wbase;
                ((unsigned int*)xsT1)[woff] = pk2(xv0[i], xv1[i]);
                ((unsigned int*)xsT2)[woff] = pk2(xv0[i] * xv0[i], xv1[i] * xv1[i]);
            }
        }

        // --- logits MFMA (B-operand straight from registers) + softmax ---
        {
            union { bf16x8 v; unsigned int u[4]; } Lo, Hi;
            Lo.u[0] = pk2(c0.x, c0.y); Lo.u[1] = pk2(c0.z, c0.w);
            Lo.u[2] = pk2(c1.x, c1.y); Lo.u[3] = pk2(c1.z, c1.w);
            Hi.u[0] = pk2(c2.x, c2.y); Hi.u[1] = pk2(c2.z, c2.w);
            Hi.u[2] = pk2(c3.x, c3.y); Hi.u[3] = pk2(c3.z, c3.w);
            f32x4 lz = {0.f, 0.f, 0.f, 0.f};
            lz = __builtin_amdgcn_mfma_f32_16x16x32_bf16(aw0, Lo.v, lz, 0, 0, 0);
            lz = __builtin_amdgcn_mfma_f32_16x16x32_bf16(aw1, Hi.v, lz, 0, 0, 0);
            float L0 = lz[0] + lb.x, L1 = lz[1] + lb.y;
            float L2 = lz[2] + lb.z, L3 = lz[3] + lb.w;
            float mx = fmaxf(fmaxf(L0, L1), fmaxf(L2, L3));
            mx = fmaxf(mx, __shfl_xor(mx, 16));
            float e0 = __expf(L0 - mx), e1 = __expf(L1 - mx);
            float e2 = __expf(L2 - mx), e3 = __expf(L3 - mx);
            float s = e0 + e1 + e2 + e3;
            s += __shfl_xor(s, 16);
            float inv = __builtin_amdgcn_rcpf(s);
            if (quad < 2) {
                float a0  = vm ? e0 * inv : 0.f, a1v = vm ? e1 * inv : 0.f;
                float a2v = vm ? e2 * inv : 0.f, a3v = vm ? e3 * inv : 0.f;
                asum_acc[0] += a0;  asum_acc[1] += a1v;
                asum_acc[2] += a2v; asum_acc[3] += a3v;
                actT[(quad * 4 + 0) * 136 + mloc] = f2bf(a0);
                actT[(quad * 4 + 1) * 136 + mloc] = f2bf(a1v);
                actT[(quad * 4 + 2) * 136 + mloc] = f2bf(a2v);
                actT[(quad * 4 + 3) * 136 + mloc] = f2bf(a3v);
            }
        }
        __syncthreads();   // B1: xsT + actT visible

        // --- einsum MFMA: wave (fvsel, tile) accumulates over 4 K-steps ---
        {
            const short* xsel = fvsel ? xsT2 : xsT1;
            const int f   = tile * 16 + ln15;
            const int fsw = f >> 3;
            #pragma unroll
            for (int ks = 0; ks < 4; ++ks) {
                bf16x8 av = *(const bf16x8*)(actT + ln15 * 136 + ks * 32 + quad * 8);
                int kblk = ks * 4 + quad;
                bf16x8 bv = *(const bf16x8*)(xsel + f * 136 + ((kblk ^ fsw) << 3));
                acc = __builtin_amdgcn_mfma_f32_16x16x32_bf16(av, bv, acc, 0, 0, 0);
            }
        }
        __syncthreads();   // B2: xsT/actT consumed, safe to overwrite next iter
        A0 = nA0; A1 = nA1; B0 = nB0; B1 = nB1;
    }

    // ---------- a_sum: asum_acc holds c=quad*4+r partials (quads 0,1) ----------
    #pragma unroll
    for (int r = 0; r < 4; ++r) {
        float v = asum_acc[r];
        v += __shfl_xor(v, 1); v += __shfl_xor(v, 2);
        v += __shfl_xor(v, 4); v += __shfl_xor(v, 8);
        asum_acc[r] = v;
    }
    if (quad < 2 && ln15 == 0) {
        #pragma unroll
        for (int r = 0; r < 4; ++r) redA[wv * 8 + quad * 4 + r] = asum_acc[r];
    }
    __syncthreads();
    if (tid < 64) {
        float v = redA[tid];
        v += __shfl_down(v, 8); v += __shfl_down(v, 16); v += __shfl_down(v, 32);
        if (tid < 8) asuml[tid] = v;
    }
    // ---------- store MFMA tiles: D layout col=ln15 (f), row=quad*4+reg (c) ----------
    if (quad < 2) {
        #pragma unroll
        for (int r = 0; r < 4; ++r)
            fvbuf[fvsel * 512 + (tile * 16 + ln15) * 8 + quad * 4 + r] = acc[r];
    }
    __syncthreads();

    // ---------- epilogue math ----------
    float fv1v = 0.f, fv2v = 0.f;
    const int f_e = tid >> 3, c_e = tid & 7;
    if (tid < 480) {
        float fv1r = fvbuf[f_e * 8 + c_e];
        float fv2r = fvbuf[512 + f_e * 8 + c_e];
        float asv  = asuml[c_e];
        float cw2v = cw2[f_e * 8 + c_e];
        float cv   = covar[f_e * 8 + c_e];
        float cwv  = cv * cv + 1e-6f;
        float rcw  = 1.0f / cwv;
        fv1v = (fv1r - asv * cw2v) * rcw;
        fv2v = (fmaf(asv * cw2v, cw2v, fv2r) - 2.0f * fv1r * cw2v) * rcw * rcw - asv;
    }

    // ---------- norm reductions: per-c sum(fv1^2), total sum(fv2^2) ----------
    {
        float p1 = fv1v * fv1v, p2 = fv2v * fv2v;
        p1 += __shfl_down(p1, 8);  p2 += __shfl_down(p2, 8);
        p1 += __shfl_down(p1, 16); p2 += __shfl_down(p2, 16);
        p1 += __shfl_down(p1, 32); p2 += __shfl_down(p2, 32);
        if (lane < 8) { redA[wv * 8 + lane] = p1; redB[wv * 8 + lane] = p2; }
    }
    __syncthreads();
    if (tid < 64) {
        float q1 = redA[tid], q2 = redB[tid];
        q1 += __shfl_down(q1, 8);  q2 += __shfl_down(q2, 8);
        q1 += __shfl_down(q1, 16); q2 += __shfl_down(q2, 16);
        q1 += __shfl_down(q1, 32); q2 += __shfl_down(q2, 32);
        if (tid < 8) { n1c_s[tid] = q1; n2c_s[tid] = q2; }
    }
    __syncthreads();
    if (tid == 0) {
        float S1 = 0.f, S2 = 0.f;
        #pragma unroll
        for (int c = 0; c < 8; ++c) {
            float rs = rsqrtf(fmaxf(n1c_s[c], 1e-12f));
            n1rs[c] = rs;
            S1 += n1c_s[c] * rs * rs;
            S2 += n2c_s[c];
        }
        scal[0] = rsqrtf(fmaxf(S1, 1e-12f));
        scal[1] = rsqrtf(fmaxf(S2, 1e-12f));
    }
    __syncthreads();
    if (tid < 480) {
        fvl[f_e * 8 + c_e]       = fv1v * n1rs[c_e] * scal[0];
        fvl[480 + f_e * 8 + c_e] = fv2v * scal[1];
    }
    __syncthreads();

    // ---------- GEMV: out[o] = fv . H[:, o] ----------
    for (int o = wv; o < ODIM; o += 8) {
        float sacc = 0.f;
        #pragma unroll 5
        for (int i = lane; i < 960; i += 64)
            sacc = fmaf(fvl[i], H[i * ODIM + o], sacc);
        sacc += __shfl_down(sacc, 32);
        sacc += __shfl_down(sacc, 16);
        sacc += __shfl_down(sacc, 8);
        sacc += __shfl_down(sacc, 4);
        sacc += __shfl_down(sacc, 2);
        sacc += __shfl_down(sacc, 1);
        if (lane == 0) out[(size_t)b * ODIM + o] = sacc;
    }
}

extern "C" void kernel_launch(void* const* d_in, const int* in_sizes, int n_in,
                              void* d_out, int out_size, void* d_ws, size_t ws_size,
                              hipStream_t stream) {
    const float* x     = (const float*)d_in[0];
    const float* W     = (const float*)d_in[1];
    const float* covar = (const float*)d_in[2];
    const float* bias  = (const float*)d_in[3];
    const float* cw2   = (const float*)d_in[4];
    const float* H     = (const float*)d_in[5];
    float* outp = (float*)d_out;

    const int Bn = in_sizes[0] / (MROW * FDIM);   // 2048
    hipLaunchKernelGGL(netfv_kernel, dim3(Bn), dim3(BLK), 0, stream,
                       x, W, covar, bias, cw2, H, outp);
}

// Round 2
// 438.813 us; speedup vs baseline: 1.1003x; 1.1003x over previous
//
#include <hip/hip_runtime.h>
#include <hip/hip_bf16.h>

#define FDIM 60
#define MROW 600
#define CDIM 8
#define ODIM 18
#define CH   128
#define NCHUNK 5
#define BLK  512

typedef short bf16x8 __attribute__((ext_vector_type(8)));
typedef float f32x4  __attribute__((ext_vector_type(4)));

// RNE pack two fp32 -> bf16x2 via v_cvt_pk_bf16_f32 (lo = low half, hi = high half)
__device__ __forceinline__ unsigned int pk2(float lo, float hi) {
    __hip_bfloat162 h2 = __float22bfloat162_rn(make_float2(lo, hi));
    unsigned int u;
    __builtin_memcpy(&u, &h2, sizeof(u));
    return u;
}
__device__ __forceinline__ short f2bf(float f) {
    __hip_bfloat16 h = __float2bfloat16(f);
    short s;
    __builtin_memcpy(&s, &h, sizeof(s));
    return s;
}

__global__ void __launch_bounds__(BLK, 4) netfv_kernel(
    const float* __restrict__ x,      // [B*M, F] fp32
    const float* __restrict__ W,      // [F, C]
    const float* __restrict__ covar,  // [F, C]
    const float* __restrict__ bias,   // [C]
    const float* __restrict__ cw2,    // [1, F, C]
    const float* __restrict__ H,      // [2*C*F, OUT]
    float* __restrict__ out)          // [B, OUT]
{
    // LDS: 17408*2 + 4352 + 2304 + 4096 + 3840 + 512 + 136 = 50,056 B
    __shared__ __align__(16) short xsT1[64 * 136];   // x   [f][m] k-major, swizzled
    __shared__ __align__(16) short xsT2[64 * 136];   // x^2 [f][m] k-major, swizzled
    __shared__ __align__(16) short actT[16 * 136];   // act [c][m] k-major (c>=8 zero)
    __shared__ __align__(16) short WtB [16 * 72];    // W^T bf16 (c>=8 / f>=60 zero)
    __shared__ __align__(16) float fvbuf[1024];      // raw fv1|fv2 [f*8+c]
    __shared__ __align__(16) float fvl[960];
    __shared__ float redA[64], redB[64];
    __shared__ float asuml[8], n1rs[8], n1c_s[8], n2c_s[8], scal[2];

    const int tid  = threadIdx.x;
    const int b    = blockIdx.x;
    const int lane = tid & 63;
    const int wv   = tid >> 6;
    const int mg   = tid >> 3;      // row-pair 0..63
    const int fs   = tid & 7;       // f-slice (8 floats)
    const int ln15 = lane & 15;
    const int quad = lane >> 4;
    const int fvsel = wv & 1;       // 0: fv1 (x), 1: fv2 (x^2)
    const int tile  = wv >> 1;      // f-tile 0..3

    const size_t rowbase = (size_t)b * (MROW * FDIM);
    const float* prow = x + rowbase + (size_t)(2 * mg) * FDIM + 8 * fs;
    const int mloc = wv * 16 + ln15;      // local m handled in logits phase

    // ---- preload chunk 0: staging regs + logits regs (same cache lines) ----
    float4 A0, A1, B0, B1;
    B0 = B1 = make_float4(0.f, 0.f, 0.f, 0.f);
    A0 = *(const float4*)prow;
    A1 = *(const float4*)(prow + FDIM);
    if (fs < 7) { B0 = *(const float4*)(prow + 4); B1 = *(const float4*)(prow + FDIM + 4); }

    float4 c0, c1, c2, c3;
    {
        const float* xr = x + rowbase + (size_t)mloc * FDIM;   // mloc < 128 < MROW
        c0 = *(const float4*)(xr + quad * 8);
        c1 = *(const float4*)(xr + quad * 8 + 4);
        c2 = *(const float4*)(xr + 32 + quad * 8);
        c3 = (quad < 3) ? *(const float4*)(xr + 36 + quad * 8)
                        : make_float4(0.f, 0.f, 0.f, 0.f);      // f60..63: W zero-padded
    }

    // --- one-time init: WtB (bf16 W^T, zero-padded), actT rows 8..15 zero ---
    {
        int c = tid >> 5, j = tid & 31;
        float v0 = (2 * j     < FDIM) ? W[(2 * j) * CDIM + (c & 7)]     : 0.f;
        float v1 = (2 * j + 1 < FDIM) ? W[(2 * j + 1) * CDIM + (c & 7)] : 0.f;
        if (c >= CDIM) { v0 = 0.f; v1 = 0.f; }
        ((unsigned int*)WtB)[c * 36 + j] = pk2(v0, v1);
    }
    {
        unsigned int* az = (unsigned int*)(actT + 8 * 136);
        for (int i = tid; i < 544; i += BLK) az[i] = 0u;
    }
    __syncthreads();

    // hoisted W A-fragments (constant across chunks) + bias fragment
    const bf16x8 aw0 = *(const bf16x8*)(WtB + ln15 * 72 + quad * 8);
    const bf16x8 aw1 = *(const bf16x8*)(WtB + ln15 * 72 + 32 + quad * 8);
    const float4 lb  = *(const float4*)(bias + (quad & 1) * 4);

    f32x4 acc = {0.f, 0.f, 0.f, 0.f};
    float asum_acc[4] = {0.f, 0.f, 0.f, 0.f};

    for (int ck = 0; ck < NCHUNK; ++ck) {
        const bool valid = (ck * CH + 2 * mg) < MROW;

        // --- prefetch NEXT chunk: staging regs AND logits regs back-to-back,
        //     so each cache line's twin read is L1/L2-hot ---
        float4 nA0, nA1, nB0, nB1, nc0, nc1, nc2, nc3;
        nA0 = nA1 = nB0 = nB1 = make_float4(0.f, 0.f, 0.f, 0.f);
        nc0 = nc1 = nc2 = nc3 = make_float4(0.f, 0.f, 0.f, 0.f);
        if (ck + 1 < NCHUNK) {
            if (((ck + 1) * CH + 2 * mg) < MROW) {
                const float* pn = prow + (size_t)(ck + 1) * (CH * FDIM);
                nA0 = *(const float4*)pn;
                nA1 = *(const float4*)(pn + FDIM);
                if (fs < 7) { nB0 = *(const float4*)(pn + 4); nB1 = *(const float4*)(pn + FDIM + 4); }
            }
            const int grow2 = (ck + 1) * CH + mloc;
            const float* xr2 = x + rowbase +
                               (size_t)((grow2 < MROW) ? grow2 : (MROW - 1)) * FDIM;
            nc0 = *(const float4*)(xr2 + quad * 8);
            nc1 = *(const float4*)(xr2 + quad * 8 + 4);
            nc2 = *(const float4*)(xr2 + 32 + quad * 8);
            if (quad < 3) nc3 = *(const float4*)(xr2 + 36 + quad * 8);
        }

        // --- stage current chunk to LDS: f-major x and x^2 (swizzled) ---
        if (valid) {
            float xv0[8] = {A0.x, A0.y, A0.z, A0.w, B0.x, B0.y, B0.z, B0.w};
            float xv1[8] = {A1.x, A1.y, A1.z, A1.w, B1.x, B1.y, B1.z, B1.w};
            const int wbase = (((mg >> 2) ^ fs) << 2) + (mg & 3);
            #pragma unroll
            for (int i = 0; i < 8; ++i) {
                int woff = (8 * fs + i) * 68 + wbase;
                ((unsigned int*)xsT1)[woff] = pk2(xv0[i], xv1[i]);
                ((unsigned int*)xsT2)[woff] = pk2(xv0[i] * xv0[i], xv1[i] * xv1[i]);
            }
        }

        // --- logits MFMA (B-operand from registers) + distributed softmax ---
        {
            const bool vm = (ck * CH + mloc) < MROW;
            union { bf16x8 v; unsigned int u[4]; } Lo, Hi;
            Lo.u[0] = pk2(c0.x, c0.y); Lo.u[1] = pk2(c0.z, c0.w);
            Lo.u[2] = pk2(c1.x, c1.y); Lo.u[3] = pk2(c1.z, c1.w);
            Hi.u[0] = pk2(c2.x, c2.y); Hi.u[1] = pk2(c2.z, c2.w);
            Hi.u[2] = pk2(c3.x, c3.y); Hi.u[3] = pk2(c3.z, c3.w);
            f32x4 lz = {0.f, 0.f, 0.f, 0.f};
            lz = __builtin_amdgcn_mfma_f32_16x16x32_bf16(aw0, Lo.v, lz, 0, 0, 0);
            lz = __builtin_amdgcn_mfma_f32_16x16x32_bf16(aw1, Hi.v, lz, 0, 0, 0);
            float L0 = lz[0] + lb.x, L1 = lz[1] + lb.y;
            float L2 = lz[2] + lb.z, L3 = lz[3] + lb.w;
            float mx = fmaxf(fmaxf(L0, L1), fmaxf(L2, L3));
            mx = fmaxf(mx, __shfl_xor(mx, 16));
            float e0 = __expf(L0 - mx), e1 = __expf(L1 - mx);
            float e2 = __expf(L2 - mx), e3 = __expf(L3 - mx);
            float s = e0 + e1 + e2 + e3;
            s += __shfl_xor(s, 16);
            float inv = __builtin_amdgcn_rcpf(s);
            if (quad < 2) {
                float a0  = vm ? e0 * inv : 0.f, a1v = vm ? e1 * inv : 0.f;
                float a2v = vm ? e2 * inv : 0.f, a3v = vm ? e3 * inv : 0.f;
                asum_acc[0] += a0;  asum_acc[1] += a1v;
                asum_acc[2] += a2v; asum_acc[3] += a3v;
                actT[(quad * 4 + 0) * 136 + mloc] = f2bf(a0);
                actT[(quad * 4 + 1) * 136 + mloc] = f2bf(a1v);
                actT[(quad * 4 + 2) * 136 + mloc] = f2bf(a2v);
                actT[(quad * 4 + 3) * 136 + mloc] = f2bf(a3v);
            }
        }
        __syncthreads();   // B1: xsT + actT visible

        // --- einsum MFMA: wave (fvsel, tile) accumulates over 4 K-steps ---
        {
            const short* xsel = fvsel ? xsT2 : xsT1;
            const int f   = tile * 16 + ln15;
            const int fsw = f >> 3;
            #pragma unroll
            for (int ks = 0; ks < 4; ++ks) {
                bf16x8 av = *(const bf16x8*)(actT + ln15 * 136 + ks * 32 + quad * 8);
                int kblk = ks * 4 + quad;
                bf16x8 bv = *(const bf16x8*)(xsel + f * 136 + ((kblk ^ fsw) << 3));
                acc = __builtin_amdgcn_mfma_f32_16x16x32_bf16(av, bv, acc, 0, 0, 0);
            }
        }
        __syncthreads();   // B2: xsT/actT consumed, safe to overwrite next iter
        A0 = nA0; A1 = nA1; B0 = nB0; B1 = nB1;
        c0 = nc0; c1 = nc1; c2 = nc2; c3 = nc3;
    }

    // ---------- a_sum: asum_acc holds c=quad*4+r partials (quads 0,1) ----------
    #pragma unroll
    for (int r = 0; r < 4; ++r) {
        float v = asum_acc[r];
        v += __shfl_xor(v, 1); v += __shfl_xor(v, 2);
        v += __shfl_xor(v, 4); v += __shfl_xor(v, 8);
        asum_acc[r] = v;
    }
    if (quad < 2 && ln15 == 0) {
        #pragma unroll
        for (int r = 0; r < 4; ++r) redA[wv * 8 + quad * 4 + r] = asum_acc[r];
    }
    __syncthreads();
    if (tid < 64) {
        float v = redA[tid];
        v += __shfl_down(v, 8); v += __shfl_down(v, 16); v += __shfl_down(v, 32);
        if (tid < 8) asuml[tid] = v;
    }
    // ---------- store MFMA tiles: D layout col=ln15 (f), row=quad*4+reg (c) ----------
    if (quad < 2) {
        #pragma unroll
        for (int r = 0; r < 4; ++r)
            fvbuf[fvsel * 512 + (tile * 16 + ln15) * 8 + quad * 4 + r] = acc[r];
    }
    __syncthreads();

    // ---------- epilogue math ----------
    float fv1v = 0.f, fv2v = 0.f;
    const int f_e = tid >> 3, c_e = tid & 7;
    if (tid < 480) {
        float fv1r = fvbuf[f_e * 8 + c_e];
        float fv2r = fvbuf[512 + f_e * 8 + c_e];
        float asv  = asuml[c_e];
        float cw2v = cw2[f_e * 8 + c_e];
        float cv   = covar[f_e * 8 + c_e];
        float cwv  = cv * cv + 1e-6f;
        float rcw  = 1.0f / cwv;
        fv1v = (fv1r - asv * cw2v) * rcw;
        fv2v = (fmaf(asv * cw2v, cw2v, fv2r) - 2.0f * fv1r * cw2v) * rcw * rcw - asv;
    }

    // ---------- norm reductions: per-c sum(fv1^2), total sum(fv2^2) ----------
    {
        float p1 = fv1v * fv1v, p2 = fv2v * fv2v;
        p1 += __shfl_down(p1, 8);  p2 += __shfl_down(p2, 8);
        p1 += __shfl_down(p1, 16); p2 += __shfl_down(p2, 16);
        p1 += __shfl_down(p1, 32); p2 += __shfl_down(p2, 32);
        if (lane < 8) { redA[wv * 8 + lane] = p1; redB[wv * 8 + lane] = p2; }
    }
    __syncthreads();
    if (tid < 64) {
        float q1 = redA[tid], q2 = redB[tid];
        q1 += __shfl_down(q1, 8);  q2 += __shfl_down(q2, 8);
        q1 += __shfl_down(q1, 16); q2 += __shfl_down(q2, 16);
        q1 += __shfl_down(q1, 32); q2 += __shfl_down(q2, 32);
        if (tid < 8) { n1c_s[tid] = q1; n2c_s[tid] = q2; }
    }
    __syncthreads();
    if (tid == 0) {
        float S1 = 0.f, S2 = 0.f;
        #pragma unroll
        for (int c = 0; c < 8; ++c) {
            float rs = rsqrtf(fmaxf(n1c_s[c], 1e-12f));
            n1rs[c] = rs;
            S1 += n1c_s[c] * rs * rs;
            S2 += n2c_s[c];
        }
        scal[0] = rsqrtf(fmaxf(S1, 1e-12f));
        scal[1] = rsqrtf(fmaxf(S2, 1e-12f));
    }
    __syncthreads();
    if (tid < 480) {
        fvl[f_e * 8 + c_e]       = fv1v * n1rs[c_e] * scal[0];
        fvl[480 + f_e * 8 + c_e] = fv2v * scal[1];
    }
    __syncthreads();

    // ---------- GEMV: out[o] = fv . H[:, o] ----------
    for (int o = wv; o < ODIM; o += 8) {
        float sacc = 0.f;
        #pragma unroll 5
        for (int i = lane; i < 960; i += 64)
            sacc = fmaf(fvl[i], H[i * ODIM + o], sacc);
        sacc += __shfl_down(sacc, 32);
        sacc += __shfl_down(sacc, 16);
        sacc += __shfl_down(sacc, 8);
        sacc += __shfl_down(sacc, 4);
        sacc += __shfl_down(sacc, 2);
        sacc += __shfl_down(sacc, 1);
        if (lane == 0) out[(size_t)b * ODIM + o] = sacc;
    }
}

extern "C" void kernel_launch(void* const* d_in, const int* in_sizes, int n_in,
                              void* d_out, int out_size, void* d_ws, size_t ws_size,
                              hipStream_t stream) {
    const float* x     = (const float*)d_in[0];
    const float* W     = (const float*)d_in[1];
    const float* covar = (const float*)d_in[2];
    const float* bias  = (const float*)d_in[3];
    const float* cw2   = (const float*)d_in[4];
    const float* H     = (const float*)d_in[5];
    float* outp = (float*)d_out;

    const int Bn = in_sizes[0] / (MROW * FDIM);   // 2048
    hipLaunchKernelGGL(netfv_kernel, dim3(Bn), dim3(BLK), 0, stream,
                       x, W, covar, bias, cw2, H, outp);
}

// Round 4
// 432.326 us; speedup vs baseline: 1.1168x; 1.0150x over previous
//
#include <hip/hip_runtime.h>
#include <hip/hip_bf16.h>

#define FDIM 60
#define MROW 600
#define CDIM 8
#define ODIM 18
#define CH   120
#define NCHUNK 5
#define BLK  512

typedef short bf16x8 __attribute__((ext_vector_type(8)));
typedef float f32x4  __attribute__((ext_vector_type(4)));

// RNE pack two fp32 -> bf16x2 via v_cvt_pk_bf16_f32 (lo = low half, hi = high half)
__device__ __forceinline__ unsigned int pk2(float lo, float hi) {
    __hip_bfloat162 h2 = __float22bfloat162_rn(make_float2(lo, hi));
    unsigned int u;
    __builtin_memcpy(&u, &h2, sizeof(u));
    return u;
}
__device__ __forceinline__ short f2bf(float f) {
    __hip_bfloat16 h = __float2bfloat16(f);
    short s;
    __builtin_memcpy(&s, &h, sizeof(s));
    return s;
}

// wave-local LDS drain (producer->consumer within one wave) + scheduler fence
#define WAVE_LGKM() do {                                          \
    asm volatile("s_waitcnt lgkmcnt(0)" ::: "memory");            \
    __builtin_amdgcn_sched_barrier(0);                            \
} while (0)
// raw barrier: drains LDS only, NOT vmcnt -> prefetch loads stay in flight
#define RAW_BAR() do {                                            \
    asm volatile("s_waitcnt lgkmcnt(0)" ::: "memory");            \
    __builtin_amdgcn_s_barrier();                                 \
    __builtin_amdgcn_sched_barrier(0);                            \
} while (0)

__global__ void __launch_bounds__(BLK, 4) netfv_kernel(
    const float* __restrict__ x,      // [B*M, F] fp32
    const float* __restrict__ W,      // [F, C]
    const float* __restrict__ covar,  // [F, C]
    const float* __restrict__ bias,   // [C]
    const float* __restrict__ cw2,    // [1, F, C]
    const float* __restrict__ H,      // [2*C*F, OUT]
    float* __restrict__ out)          // [B, OUT]
{
    // LDS ~72.6 KB -> 2 blocks/CU
    __shared__ __align__(16) short xsT1[64 * 136];   // x   [f][m] k-major, swizzled
    __shared__ __align__(16) short xsT2[64 * 136];   // x^2 [f][m] k-major, swizzled
    __shared__ __align__(16) short xsM [128 * 88];   // x   [m][f] m-major (rows 120..127 zero)
    __shared__ __align__(16) short actT[16 * 136];   // act [c][m] k-major (c>=8 zero)
    __shared__ __align__(16) short WtB [16 * 72];    // W^T bf16 (c>=8 / f>=60 zero)
    __shared__ __align__(16) float fvbuf[1024];      // raw fv1|fv2 [f*8+c]
    __shared__ __align__(16) float fvl[960];
    __shared__ float redA[64], redB[64];
    __shared__ float asuml[8], n1rs[8], n1c_s[8], n2c_s[8], scal[2];

    const int tid  = threadIdx.x;
    const int b    = blockIdx.x;
    const int lane = tid & 63;
    const int wv   = tid >> 6;
    const int mg   = tid >> 3;      // row-pair 0..63 (0..59 active)
    const int fs   = tid & 7;       // f-slice (8 floats)
    const int ln15 = lane & 15;
    const int quad = lane >> 4;
    const int fvsel = wv & 1;       // 0: fv1 (x), 1: fv2 (x^2)
    const int tile  = wv >> 1;      // f-tile 0..3

    const size_t rowbase = (size_t)b * (MROW * FDIM);
    const bool stv = (mg < 60);     // staging-valid (loop-invariant: 600 = 5*120)
    const float* prow = x + rowbase + (size_t)(2 * mg) * FDIM + 8 * fs;
    const int mloc = wv * 16 + ln15;          // local m in logits phase
    const bool vm = (mloc < CH);              // rows 120..127 dead (loop-invariant)

    // ---- preload chunk 0 staging regs ----
    float4 A0, A1, B0, B1;
    A0 = A1 = B0 = B1 = make_float4(0.f, 0.f, 0.f, 0.f);
    if (stv) {
        A0 = *(const float4*)prow;
        A1 = *(const float4*)(prow + FDIM);
        if (fs < 7) { B0 = *(const float4*)(prow + 4); B1 = *(const float4*)(prow + FDIM + 4); }
    }

    // --- one-time init: WtB; zero xsT1/xsT2 entirely (dead swizzled octets must
    //     be 0.0 bf16, not garbage); zero xsM rows 120..127; zero actT rows 8..15 ---
    {
        int c = tid >> 5, j = tid & 31;
        float v0 = (2 * j     < FDIM) ? W[(2 * j) * CDIM + (c & 7)]     : 0.f;
        float v1 = (2 * j + 1 < FDIM) ? W[(2 * j + 1) * CDIM + (c & 7)] : 0.f;
        if (c >= CDIM) { v0 = 0.f; v1 = 0.f; }
        ((unsigned int*)WtB)[c * 36 + j] = pk2(v0, v1);
    }
    {
        unsigned int* z1 = (unsigned int*)xsT1;
        unsigned int* z2 = (unsigned int*)xsT2;
        for (int i = tid; i < 64 * 68; i += BLK) { z1[i] = 0u; z2[i] = 0u; }
        unsigned int* zm = (unsigned int*)(xsM + 120 * 88);
        for (int i = tid; i < 8 * 44; i += BLK) zm[i] = 0u;
        unsigned int* az = (unsigned int*)(actT + 8 * 136);
        for (int i = tid; i < 544; i += BLK) az[i] = 0u;
    }
    __syncthreads();   // init visible to all (full sync OK here, once)

    // hoisted W A-fragments (constant across chunks) + bias fragment
    const bf16x8 aw0 = *(const bf16x8*)(WtB + ln15 * 72 + quad * 8);
    const bf16x8 aw1 = *(const bf16x8*)(WtB + ln15 * 72 + 32 + quad * 8);
    const float4 lb  = *(const float4*)(bias + (quad & 1) * 4);

    f32x4 acc = {0.f, 0.f, 0.f, 0.f};
    float asum_acc[4] = {0.f, 0.f, 0.f, 0.f};

    for (int ck = 0; ck < NCHUNK; ++ck) {
        // --- prefetch next chunk into registers (no barrier in this loop drains
        //     vmcnt, so these float until their use in next iteration's pack) ---
        float4 nA0, nA1, nB0, nB1;
        nA0 = nA1 = nB0 = nB1 = make_float4(0.f, 0.f, 0.f, 0.f);
        if (ck + 1 < NCHUNK && stv) {
            const float* pn = prow + (size_t)(ck + 1) * (CH * FDIM);
            nA0 = *(const float4*)pn;
            nA1 = *(const float4*)(pn + FDIM);
            if (fs < 7) { nB0 = *(const float4*)(pn + 4); nB1 = *(const float4*)(pn + FDIM + 4); }
        }

        // --- stage current chunk: xsM (m-major, b128) + xsT1/xsT2 (f-major scatter) ---
        if (stv) {
            float xv0[8] = {A0.x, A0.y, A0.z, A0.w, B0.x, B0.y, B0.z, B0.w};
            float xv1[8] = {A1.x, A1.y, A1.z, A1.w, B1.x, B1.y, B1.z, B1.w};
            // m-major rows for logits B-operand: 2 x ds_write_b128
            {
                unsigned int q0 = pk2(xv0[0], xv0[1]), q1 = pk2(xv0[2], xv0[3]);
                unsigned int q2 = pk2(xv0[4], xv0[5]), q3 = pk2(xv0[6], xv0[7]);
                *(uint4*)(xsM + (2 * mg) * 88 + 8 * fs) = make_uint4(q0, q1, q2, q3);
                unsigned int s0 = pk2(xv1[0], xv1[1]), s1 = pk2(xv1[2], xv1[3]);
                unsigned int s2 = pk2(xv1[4], xv1[5]), s3 = pk2(xv1[6], xv1[7]);
                *(uint4*)(xsM + (2 * mg + 1) * 88 + 8 * fs) = make_uint4(s0, s1, s2, s3);
            }
            // f-major (k=m) for einsum B-operands, swizzled
            const int wbase = (((mg >> 2) ^ fs) << 2) + (mg & 3);
            #pragma unroll
            for (int i = 0; i < 8; ++i) {
                int woff = (8 * fs + i) * 68 + wbase;
                ((unsigned int*)xsT1)[woff] = pk2(xv0[i], xv1[i]);
                ((unsigned int*)xsT2)[woff] = pk2(xv0[i] * xv0[i], xv1[i] * xv1[i]);
            }
        }

        // --- logits: INTRA-WAVE consumer of xsM (wave w reads rows 16w..16w+15,
        //     which wave w's own threads staged) -> wave-local lgkm wait only ---
        WAVE_LGKM();
        {
            bf16x8 bv0 = *(const bf16x8*)(xsM + mloc * 88 + quad * 8);
            bf16x8 bv1 = *(const bf16x8*)(xsM + mloc * 88 + 32 + quad * 8);
            f32x4 lz = {0.f, 0.f, 0.f, 0.f};
            lz = __builtin_amdgcn_mfma_f32_16x16x32_bf16(aw0, bv0, lz, 0, 0, 0);
            lz = __builtin_amdgcn_mfma_f32_16x16x32_bf16(aw1, bv1, lz, 0, 0, 0);
            float L0 = lz[0] + lb.x, L1 = lz[1] + lb.y;
            float L2 = lz[2] + lb.z, L3 = lz[3] + lb.w;
            float mx = fmaxf(fmaxf(L0, L1), fmaxf(L2, L3));
            mx = fmaxf(mx, __shfl_xor(mx, 16));
            float e0 = __expf(L0 - mx), e1 = __expf(L1 - mx);
            float e2 = __expf(L2 - mx), e3 = __expf(L3 - mx);
            float s = e0 + e1 + e2 + e3;
            s += __shfl_xor(s, 16);
            float inv = __builtin_amdgcn_rcpf(s);
            if (quad < 2) {
                float a0  = vm ? e0 * inv : 0.f, a1v = vm ? e1 * inv : 0.f;
                float a2v = vm ? e2 * inv : 0.f, a3v = vm ? e3 * inv : 0.f;
                asum_acc[0] += a0;  asum_acc[1] += a1v;
                asum_acc[2] += a2v; asum_acc[3] += a3v;
                actT[(quad * 4 + 0) * 136 + mloc] = f2bf(a0);
                actT[(quad * 4 + 1) * 136 + mloc] = f2bf(a1v);
                actT[(quad * 4 + 2) * 136 + mloc] = f2bf(a2v);
                actT[(quad * 4 + 3) * 136 + mloc] = f2bf(a3v);
            }
        }
        RAW_BAR();   // B2: xsT + actT visible to all waves (no vmcnt drain)

        // --- einsum MFMA: wave (fvsel, tile) accumulates over 4 K-steps ---
        {
            const short* xsel = fvsel ? xsT2 : xsT1;
            const int f   = tile * 16 + ln15;
            const int fsw = f >> 3;
            #pragma unroll
            for (int ks = 0; ks < 4; ++ks) {
                bf16x8 av = *(const bf16x8*)(actT + ln15 * 136 + ks * 32 + quad * 8);
                int kblk = ks * 4 + quad;
                bf16x8 bv = *(const bf16x8*)(xsel + f * 136 + ((kblk ^ fsw) << 3));
                acc = __builtin_amdgcn_mfma_f32_16x16x32_bf16(av, bv, acc, 0, 0, 0);
            }
        }
        RAW_BAR();   // B3: xsT/xsM/actT consumed; next iter may overwrite

        A0 = nA0; A1 = nA1; B0 = nB0; B1 = nB1;
    }

    // ---------- a_sum: asum_acc holds c=quad*4+r partials (quads 0,1) ----------
    #pragma unroll
    for (int r = 0; r < 4; ++r) {
        float v = asum_acc[r];
        v += __shfl_xor(v, 1); v += __shfl_xor(v, 2);
        v += __shfl_xor(v, 4); v += __shfl_xor(v, 8);
        asum_acc[r] = v;
    }
    if (quad < 2 && ln15 == 0) {
        #pragma unroll
        for (int r = 0; r < 4; ++r) redA[wv * 8 + quad * 4 + r] = asum_acc[r];
    }
    __syncthreads();
    if (tid < 64) {
        float v = redA[tid];
        v += __shfl_down(v, 8); v += __shfl_down(v, 16); v += __shfl_down(v, 32);
        if (tid < 8) asuml[tid] = v;
    }
    // ---------- store MFMA tiles: D layout col=ln15 (f), row=quad*4+reg (c) ----------
    if (quad < 2) {
        #pragma unroll
        for (int r = 0; r < 4; ++r)
            fvbuf[fvsel * 512 + (tile * 16 + ln15) * 8 + quad * 4 + r] = acc[r];
    }
    __syncthreads();

    // ---------- epilogue math ----------
    float fv1v = 0.f, fv2v = 0.f;
    const int f_e = tid >> 3, c_e = tid & 7;
    if (tid < 480) {
        float fv1r = fvbuf[f_e * 8 + c_e];
        float fv2r = fvbuf[512 + f_e * 8 + c_e];
        float asv  = asuml[c_e];
        float cw2v = cw2[f_e * 8 + c_e];
        float cv   = covar[f_e * 8 + c_e];
        float cwv  = cv * cv + 1e-6f;
        float rcw  = 1.0f / cwv;
        fv1v = (fv1r - asv * cw2v) * rcw;
        fv2v = (fmaf(asv * cw2v, cw2v, fv2r) - 2.0f * fv1r * cw2v) * rcw * rcw - asv;
    }

    // ---------- norm reductions: per-c sum(fv1^2), total sum(fv2^2) ----------
    {
        float p1 = fv1v * fv1v, p2 = fv2v * fv2v;
        p1 += __shfl_down(p1, 8);  p2 += __shfl_down(p2, 8);
        p1 += __shfl_down(p1, 16); p2 += __shfl_down(p2, 16);
        p1 += __shfl_down(p1, 32); p2 += __shfl_down(p2, 32);
        if (lane < 8) { redA[wv * 8 + lane] = p1; redB[wv * 8 + lane] = p2; }
    }
    __syncthreads();
    if (tid < 64) {
        float q1 = redA[tid], q2 = redB[tid];
        q1 += __shfl_down(q1, 8);  q2 += __shfl_down(q2, 8);
        q1 += __shfl_down(q1, 16); q2 += __shfl_down(q2, 16);
        q1 += __shfl_down(q1, 32); q2 += __shfl_down(q2, 32);
        if (tid < 8) { n1c_s[tid] = q1; n2c_s[tid] = q2; }
    }
    __syncthreads();
    if (tid == 0) {
        float S1 = 0.f, S2 = 0.f;
        #pragma unroll
        for (int c = 0; c < 8; ++c) {
            float rs = rsqrtf(fmaxf(n1c_s[c], 1e-12f));
            n1rs[c] = rs;
            S1 += n1c_s[c] * rs * rs;
            S2 += n2c_s[c];
        }
        scal[0] = rsqrtf(fmaxf(S1, 1e-12f));
        scal[1] = rsqrtf(fmaxf(S2, 1e-12f));
    }
    __syncthreads();
    if (tid < 480) {
        fvl[f_e * 8 + c_e]       = fv1v * n1rs[c_e] * scal[0];
        fvl[480 + f_e * 8 + c_e] = fv2v * scal[1];
    }
    __syncthreads();

    // ---------- GEMV: out[o] = fv . H[:, o] ----------
    for (int o = wv; o < ODIM; o += 8) {
        float sacc = 0.f;
        #pragma unroll 5
        for (int i = lane; i < 960; i += 64)
            sacc = fmaf(fvl[i], H[i * ODIM + o], sacc);
        sacc += __shfl_down(sacc, 32);
        sacc += __shfl_down(sacc, 16);
        sacc += __shfl_down(sacc, 8);
        sacc += __shfl_down(sacc, 4);
        sacc += __shfl_down(sacc, 2);
        sacc += __shfl_down(sacc, 1);
        if (lane == 0) out[(size_t)b * ODIM + o] = sacc;
    }
}

extern "C" void kernel_launch(void* const* d_in, const int* in_sizes, int n_in,
                              void* d_out, int out_size, void* d_ws, size_t ws_size,
                              hipStream_t stream) {
    const float* x     = (const float*)d_in[0];
    const float* W     = (const float*)d_in[1];
    const float* covar = (const float*)d_in[2];
    const float* bias  = (const float*)d_in[3];
    const float* cw2   = (const float*)d_in[4];
    const float* H     = (const float*)d_in[5];
    float* outp = (float*)d_out;

    const int Bn = in_sizes[0] / (MROW * FDIM);   // 2048
    hipLaunchKernelGGL(netfv_kernel, dim3(Bn), dim3(BLK), 0, stream,
                       x, W, covar, bias, cw2, H, outp);
}

// Round 6
// 430.885 us; speedup vs baseline: 1.1205x; 1.0033x over previous
//
#include <hip/hip_runtime.h>
#include <hip/hip_bf16.h>

#define FDIM 60
#define MROW 600
#define CDIM 8
#define ODIM 18
#define CH   120
#define NCHUNK 5
#define BLK  512

typedef short bf16x8 __attribute__((ext_vector_type(8)));
typedef float f32x4  __attribute__((ext_vector_type(4)));

// RNE pack two fp32 -> bf16x2 via v_cvt_pk_bf16_f32 (lo = low half, hi = high half)
__device__ __forceinline__ unsigned int pk2(float lo, float hi) {
    __hip_bfloat162 h2 = __float22bfloat162_rn(make_float2(lo, hi));
    unsigned int u;
    __builtin_memcpy(&u, &h2, sizeof(u));
    return u;
}
__device__ __forceinline__ short f2bf(float f) {
    __hip_bfloat16 h = __float2bfloat16(f);
    short s;
    __builtin_memcpy(&s, &h, sizeof(s));
    return s;
}

// wave-local LDS drain (producer->consumer within one wave) + scheduler fence
#define WAVE_LGKM() do {                                          \
    asm volatile("s_waitcnt lgkmcnt(0)" ::: "memory");            \
    __builtin_amdgcn_sched_barrier(0);                            \
} while (0)
// raw barrier: drains LDS only, NOT vmcnt -> prefetch loads stay in flight
#define RAW_BAR() do {                                            \
    asm volatile("s_waitcnt lgkmcnt(0)" ::: "memory");            \
    __builtin_amdgcn_s_barrier();                                 \
    __builtin_amdgcn_sched_barrier(0);                            \
} while (0)

__global__ void __launch_bounds__(BLK, 6) netfv_kernel(
    const float* __restrict__ x,      // [B*M, F] fp32
    const float* __restrict__ W,      // [F, C]
    const float* __restrict__ covar,  // [F, C]
    const float* __restrict__ bias,   // [C]
    const float* __restrict__ cw2,    // [1, F, C]
    const float* __restrict__ H,      // [2*C*F, OUT]
    float* __restrict__ out)          // [B, OUT]
{
    // LDS diet: 17408 + 17280 + 4352 + 2304 = 41,344 B -> 3 blocks/CU.
    // x^2 buffer removed (squared in-register at einsum); epilogue buffers
    // overlaid on xsT1/actT (dead after final loop barrier, ordered by B3).
    __shared__ __align__(16) short xsT1[64 * 136];   // x [f][m] k-major, swizzled
    __shared__ __align__(16) short xsM [120 * 72];   // x [m][f] m-major
    __shared__ __align__(16) short actT[16 * 136];   // act [c][m] k-major (c>=8 zero)
    __shared__ __align__(16) short WtB [16 * 72];    // W^T bf16 (c>=8 / f>=60 zero)

    // epilogue overlays (used only after the K-loop's final RAW_BAR)
    float* const fvbuf = (float*)xsT1;          // 1024 f
    float* const fvl   = (float*)xsT1 + 1024;   // 960 f   (7936 B <= 17408 B)
    float* const redA  = (float*)actT;          // 64 f
    float* const redB  = redA + 64;             // 64 f
    float* const asuml = redB + 64;             // 8 f
    float* const n1rs  = asuml + 8;             // 8 f
    float* const n1c_s = n1rs + 8;              // 8 f
    float* const n2c_s = n1c_s + 8;             // 8 f
    float* const scal  = n2c_s + 8;             // 2 f   (648 B <= 4352 B)

    const int tid  = threadIdx.x;
    const int b    = blockIdx.x;
    const int lane = tid & 63;
    const int wv   = tid >> 6;
    const int mg   = tid >> 3;      // row-pair 0..63 (0..59 active)
    const int fs   = tid & 7;       // f-slice (8 floats)
    const int ln15 = lane & 15;
    const int quad = lane >> 4;
    const int fvsel = wv & 1;       // 0: fv1 (x), 1: fv2 (x^2, squared in-reg)
    const int tile  = wv >> 1;      // f-tile 0..3

    const size_t rowbase = (size_t)b * (MROW * FDIM);
    const bool stv = (mg < 60);     // staging-valid (loop-invariant: 600 = 5*120)
    const float* prow = x + rowbase + (size_t)(2 * mg) * FDIM + 8 * fs;
    const int mloc = wv * 16 + ln15;          // local m in logits phase
    const bool vm = (mloc < CH);              // rows 120..127 dead (loop-invariant)
    const int mrow = vm ? mloc : 0;           // clamped xsM read row (result zeroed)

    // ---- preload chunk 0 staging regs ----
    float4 A0, A1, B0, B1;
    A0 = A1 = B0 = B1 = make_float4(0.f, 0.f, 0.f, 0.f);
    if (stv) {
        A0 = *(const float4*)prow;
        A1 = *(const float4*)(prow + FDIM);
        if (fs < 7) { B0 = *(const float4*)(prow + 4); B1 = *(const float4*)(prow + FDIM + 4); }
    }

    // --- one-time init: WtB; zero xsT1 entirely (dead swizzled octets must be
    //     0.0 bf16); zero actT rows 8..15 ---
    {
        int c = tid >> 5, j = tid & 31;
        float v0 = (2 * j     < FDIM) ? W[(2 * j) * CDIM + (c & 7)]     : 0.f;
        float v1 = (2 * j + 1 < FDIM) ? W[(2 * j + 1) * CDIM + (c & 7)] : 0.f;
        if (c >= CDIM) { v0 = 0.f; v1 = 0.f; }
        ((unsigned int*)WtB)[c * 36 + j] = pk2(v0, v1);
    }
    {
        unsigned int* z1 = (unsigned int*)xsT1;
        for (int i = tid; i < 64 * 68; i += BLK) z1[i] = 0u;
        unsigned int* az = (unsigned int*)(actT + 8 * 136);
        for (int i = tid; i < 544; i += BLK) az[i] = 0u;
    }
    __syncthreads();   // init visible to all (full sync OK here, once)

    // hoisted W A-fragments (constant across chunks) + bias fragment
    const bf16x8 aw0 = *(const bf16x8*)(WtB + ln15 * 72 + quad * 8);
    const bf16x8 aw1 = *(const bf16x8*)(WtB + ln15 * 72 + 32 + quad * 8);
    const float4 lb  = *(const float4*)(bias + (quad & 1) * 4);

    f32x4 acc = {0.f, 0.f, 0.f, 0.f};
    float asum_acc[4] = {0.f, 0.f, 0.f, 0.f};

    for (int ck = 0; ck < NCHUNK; ++ck) {
        // --- stage current chunk: xsM (m-major, b128) + xsT1 (f-major scatter).
        //     Consumes A0..B1 so they die here (keeps live range off the
        //     prefetch window -> fits the 85-VGPR cap without spills). ---
        if (stv) {
            float xv0[8] = {A0.x, A0.y, A0.z, A0.w, B0.x, B0.y, B0.z, B0.w};
            float xv1[8] = {A1.x, A1.y, A1.z, A1.w, B1.x, B1.y, B1.z, B1.w};
            // m-major rows for logits B-operand: 2 x ds_write_b128
            {
                unsigned int q0 = pk2(xv0[0], xv0[1]), q1 = pk2(xv0[2], xv0[3]);
                unsigned int q2 = pk2(xv0[4], xv0[5]), q3 = pk2(xv0[6], xv0[7]);
                *(uint4*)(xsM + (2 * mg) * 72 + 8 * fs) = make_uint4(q0, q1, q2, q3);
                unsigned int s0 = pk2(xv1[0], xv1[1]), s1 = pk2(xv1[2], xv1[3]);
                unsigned int s2 = pk2(xv1[4], xv1[5]), s3 = pk2(xv1[6], xv1[7]);
                *(uint4*)(xsM + (2 * mg + 1) * 72 + 8 * fs) = make_uint4(s0, s1, s2, s3);
            }
            // f-major (k=m) for einsum B-operand, swizzled
            const int wbase = (((mg >> 2) ^ fs) << 2) + (mg & 3);
            #pragma unroll
            for (int i = 0; i < 8; ++i) {
                int woff = (8 * fs + i) * 68 + wbase;
                ((unsigned int*)xsT1)[woff] = pk2(xv0[i], xv1[i]);
            }
        }
        __builtin_amdgcn_sched_barrier(0);   // pin: pack above, prefetch below

        // --- prefetch next chunk (issued after pack: A0..B1 dead, regs reuse;
        //     in flight across logits+einsum, no vmcnt drain until next pack) ---
        float4 nA0, nA1, nB0, nB1;
        nA0 = nA1 = nB0 = nB1 = make_float4(0.f, 0.f, 0.f, 0.f);
        if (ck + 1 < NCHUNK && stv) {
            const float* pn = prow + (size_t)(ck + 1) * (CH * FDIM);
            nA0 = *(const float4*)pn;
            nA1 = *(const float4*)(pn + FDIM);
            if (fs < 7) { nB0 = *(const float4*)(pn + 4); nB1 = *(const float4*)(pn + FDIM + 4); }
        }

        // --- logits: INTRA-WAVE consumer of xsM (wave w reads rows 16w..16w+15,
        //     which wave w's own threads staged) -> wave-local lgkm wait only.
        //     (vm-false lanes read clamped row 0 cross-wave: benign, results
        //     are discarded by the vm selects below and never cross lanes.) ---
        WAVE_LGKM();
        {
            bf16x8 bv0 = *(const bf16x8*)(xsM + mrow * 72 + quad * 8);
            bf16x8 bv1 = *(const bf16x8*)(xsM + mrow * 72 + 32 + quad * 8);
            f32x4 lz = {0.f, 0.f, 0.f, 0.f};
            lz = __builtin_amdgcn_mfma_f32_16x16x32_bf16(aw0, bv0, lz, 0, 0, 0);
            lz = __builtin_amdgcn_mfma_f32_16x16x32_bf16(aw1, bv1, lz, 0, 0, 0);
            float L0 = lz[0] + lb.x, L1 = lz[1] + lb.y;
            float L2 = lz[2] + lb.z, L3 = lz[3] + lb.w;
            float mx = fmaxf(fmaxf(L0, L1), fmaxf(L2, L3));
            mx = fmaxf(mx, __shfl_xor(mx, 16));
            float e0 = __expf(L0 - mx), e1 = __expf(L1 - mx);
            float e2 = __expf(L2 - mx), e3 = __expf(L3 - mx);
            float s = e0 + e1 + e2 + e3;
            s += __shfl_xor(s, 16);
            float inv = __builtin_amdgcn_rcpf(s);
            if (quad < 2) {
                float a0  = vm ? e0 * inv : 0.f, a1v = vm ? e1 * inv : 0.f;
                float a2v = vm ? e2 * inv : 0.f, a3v = vm ? e3 * inv : 0.f;
                asum_acc[0] += a0;  asum_acc[1] += a1v;
                asum_acc[2] += a2v; asum_acc[3] += a3v;
                actT[(quad * 4 + 0) * 136 + mloc] = f2bf(a0);
                actT[(quad * 4 + 1) * 136 + mloc] = f2bf(a1v);
                actT[(quad * 4 + 2) * 136 + mloc] = f2bf(a2v);
                actT[(quad * 4 + 3) * 136 + mloc] = f2bf(a3v);
            }
        }
        RAW_BAR();   // B2: xsT1 + actT visible to all waves (no vmcnt drain)

        // --- einsum MFMA: wave (fvsel, tile) accumulates over 4 K-steps.
        //     fv2 waves square the bf16 x in-register (exact in f32 + RNE pack) ---
        {
            const int f   = tile * 16 + ln15;
            const int fsw = f >> 3;
            #pragma unroll
            for (int ks = 0; ks < 4; ++ks) {
                bf16x8 av = *(const bf16x8*)(actT + ln15 * 136 + ks * 32 + quad * 8);
                int kblk = ks * 4 + quad;
                bf16x8 bv = *(const bf16x8*)(xsT1 + f * 136 + ((kblk ^ fsw) << 3));
                if (fvsel) {
                    union { bf16x8 v; unsigned short us[8]; unsigned int u[4]; } in, sq;
                    in.v = bv;
                    #pragma unroll
                    for (int p = 0; p < 4; ++p) {
                        float lo = __uint_as_float((unsigned)in.us[2 * p]     << 16);
                        float hi = __uint_as_float((unsigned)in.us[2 * p + 1] << 16);
                        sq.u[p] = pk2(lo * lo, hi * hi);
                    }
                    bv = sq.v;
                }
                acc = __builtin_amdgcn_mfma_f32_16x16x32_bf16(av, bv, acc, 0, 0, 0);
            }
        }
        RAW_BAR();   // B3: xsT1/xsM/actT consumed; next iter may overwrite

        A0 = nA0; A1 = nA1; B0 = nB0; B1 = nB1;
    }

    // ---------- a_sum: asum_acc holds c=quad*4+r partials (quads 0,1) ----------
    #pragma unroll
    for (int r = 0; r < 4; ++r) {
        float v = asum_acc[r];
        v += __shfl_xor(v, 1); v += __shfl_xor(v, 2);
        v += __shfl_xor(v, 4); v += __shfl_xor(v, 8);
        asum_acc[r] = v;
    }
    if (quad < 2 && ln15 == 0) {
        #pragma unroll
        for (int r = 0; r < 4; ++r) redA[wv * 8 + quad * 4 + r] = asum_acc[r];
    }
    __syncthreads();
    if (tid < 64) {
        float v = redA[tid];
        v += __shfl_down(v, 8); v += __shfl_down(v, 16); v += __shfl_down(v, 32);
        if (tid < 8) asuml[tid] = v;
    }
    // ---------- store MFMA tiles: D layout col=ln15 (f), row=quad*4+reg (c) ----------
    if (quad < 2) {
        #pragma unroll
        for (int r = 0; r < 4; ++r)
            fvbuf[fvsel * 512 + (tile * 16 + ln15) * 8 + quad * 4 + r] = acc[r];
    }
    __syncthreads();

    // ---------- epilogue math ----------
    float fv1v = 0.f, fv2v = 0.f;
    const int f_e = tid >> 3, c_e = tid & 7;
    if (tid < 480) {
        float fv1r = fvbuf[f_e * 8 + c_e];
        float fv2r = fvbuf[512 + f_e * 8 + c_e];
        float asv  = asuml[c_e];
        float cw2v = cw2[f_e * 8 + c_e];
        float cv   = covar[f_e * 8 + c_e];
        float cwv  = cv * cv + 1e-6f;
        float rcw  = 1.0f / cwv;
        fv1v = (fv1r - asv * cw2v) * rcw;
        fv2v = (fmaf(asv * cw2v, cw2v, fv2r) - 2.0f * fv1r * cw2v) * rcw * rcw - asv;
    }

    // ---------- norm reductions: per-c sum(fv1^2), total sum(fv2^2) ----------
    {
        float p1 = fv1v * fv1v, p2 = fv2v * fv2v;
        p1 += __shfl_down(p1, 8);  p2 += __shfl_down(p2, 8);
        p1 += __shfl_down(p1, 16); p2 += __shfl_down(p2, 16);
        p1 += __shfl_down(p1, 32); p2 += __shfl_down(p2, 32);
        if (lane < 8) { redA[wv * 8 + lane] = p1; redB[wv * 8 + lane] = p2; }
    }
    __syncthreads();
    if (tid < 64) {
        float q1 = redA[tid], q2 = redB[tid];
        q1 += __shfl_down(q1, 8);  q2 += __shfl_down(q2, 8);
        q1 += __shfl_down(q1, 16); q2 += __shfl_down(q2, 16);
        q1 += __shfl_down(q1, 32); q2 += __shfl_down(q2, 32);
        if (tid < 8) { n1c_s[tid] = q1; n2c_s[tid] = q2; }
    }
    __syncthreads();
    if (tid == 0) {
        float S1 = 0.f, S2 = 0.f;
        #pragma unroll
        for (int c = 0; c < 8; ++c) {
            float rs = rsqrtf(fmaxf(n1c_s[c], 1e-12f));
            n1rs[c] = rs;
            S1 += n1c_s[c] * rs * rs;
            S2 += n2c_s[c];
        }
        scal[0] = rsqrtf(fmaxf(S1, 1e-12f));
        scal[1] = rsqrtf(fmaxf(S2, 1e-12f));
    }
    __syncthreads();
    if (tid < 480) {
        fvl[f_e * 8 + c_e]       = fv1v * n1rs[c_e] * scal[0];
        fvl[480 + f_e * 8 + c_e] = fv2v * scal[1];
    }
    __syncthreads();

    // ---------- GEMV: out[o] = fv . H[:, o] ----------
    for (int o = wv; o < ODIM; o += 8) {
        float sacc = 0.f;
        #pragma unroll 5
        for (int i = lane; i < 960; i += 64)
            sacc = fmaf(fvl[i], H[i * ODIM + o], sacc);
        sacc += __shfl_down(sacc, 32);
        sacc += __shfl_down(sacc, 16);
        sacc += __shfl_down(sacc, 8);
        sacc += __shfl_down(sacc, 4);
        sacc += __shfl_down(sacc, 2);
        sacc += __shfl_down(sacc, 1);
        if (lane == 0) out[(size_t)b * ODIM + o] = sacc;
    }
}

extern "C" void kernel_launch(void* const* d_in, const int* in_sizes, int n_in,
                              void* d_out, int out_size, void* d_ws, size_t ws_size,
                              hipStream_t stream) {
    const float* x     = (const float*)d_in[0];
    const float* W     = (const float*)d_in[1];
    const float* covar = (const float*)d_in[2];
    const float* bias  = (const float*)d_in[3];
    const float* cw2   = (const float*)d_in[4];
    const float* H     = (const float*)d_in[5];
    float* outp = (float*)d_out;

    const int Bn = in_sizes[0] / (MROW * FDIM);   // 2048
    hipLaunchKernelGGL(netfv_kernel, dim3(Bn), dim3(BLK), 0, stream,
                       x, W, covar, bias, cw2, H, outp);
}